// Round 1
// baseline (1091.360 us; speedup 1.0000x reference)
//
#include <hip/hip_runtime.h>
#include <hip/hip_bf16.h>
#include <math.h>

// GridEncoder (instant-NGP hash grid) forward.
// B = 1<<20 points, 3D input, 16 levels x 2 channels, log2_hashmap=19,
// base_res=16, desired_res=2048. Output [B, 32] float32, level-major.

#define NUM_LEVELS 16
#define BLOCK 256
#define B_POINTS (1u << 20)

struct Params {
    float    scale[NUM_LEVELS];    // exp2(l*S)*16 - 1, fp32 (matches np.float32 cast)
    unsigned offset[NUM_LEVELS];   // level start row in embedding table
    unsigned G[NUM_LEVELS];        // verts per dim = ceil(scale)+2
    unsigned hashedMask;           // bit l set -> hashed level (hashmap = 2^19)
};

__global__ __launch_bounds__(BLOCK) void grid_encode_kernel(
    const float* __restrict__ inp,     // [B,3]
    const float2* __restrict__ emb,    // [N_PARAMS] as float2 rows
    float* __restrict__ out,           // [B,32]
    Params p)
{
    const unsigned b = blockIdx.x * BLOCK + threadIdx.x;

    // x = (input + 1) / 2  -- replicate numpy fp32: add then /2 (== *0.5 exactly)
    const float i0 = inp[3u * b + 0];
    const float i1 = inp[3u * b + 1];
    const float i2 = inp[3u * b + 2];
    const float x0 = __fmul_rn(__fadd_rn(i0, 1.0f), 0.5f);
    const float x1 = __fmul_rn(__fadd_rn(i1, 1.0f), 0.5f);
    const float x2 = __fmul_rn(__fadd_rn(i2, 1.0f), 0.5f);

    float o[2 * NUM_LEVELS];

#pragma unroll
    for (int l = 0; l < NUM_LEVELS; ++l) {
        const float s = p.scale[l];
        // pos = x*scale + 0.5 -- separate fp32 mul and add (no fma), bit-matches numpy
        const float p0 = __fadd_rn(__fmul_rn(x0, s), 0.5f);
        const float p1 = __fadd_rn(__fmul_rn(x1, s), 0.5f);
        const float p2 = __fadd_rn(__fmul_rn(x2, s), 0.5f);
        const float g0 = floorf(p0), g1 = floorf(p1), g2 = floorf(p2);
        const float f0 = __fsub_rn(p0, g0);
        const float f1 = __fsub_rn(p1, g1);
        const float f2 = __fsub_rn(p2, g2);
        const unsigned u0 = (unsigned)g0, u1 = (unsigned)g1, u2 = (unsigned)g2;

        const unsigned G    = p.G[l];
        const unsigned base = p.offset[l];
        const bool hashed   = (p.hashedMask >> l) & 1u;
        const float m0 = __fsub_rn(1.0f, f0);
        const float m1 = __fsub_rn(1.0f, f1);
        const float m2 = __fsub_rn(1.0f, f2);

        float a0 = 0.0f, a1 = 0.0f;
#pragma unroll
        for (int k = 0; k < 8; ++k) {
            const unsigned bit0 = (k >> 2) & 1;  // dim0 bit (meshgrid 'ij' order)
            const unsigned bit1 = (k >> 1) & 1;
            const unsigned bit2 = k & 1;
            const unsigned c0 = u0 + bit0;
            const unsigned c1 = u1 + bit1;
            const unsigned c2 = u2 + bit2;
            unsigned idx;
            if (hashed) {
                // torch-ngp fast_hash primes {1, 2654435761, 805459861}; hashmap = 2^19
                idx = (c0 ^ (c1 * 2654435761u) ^ (c2 * 805459861u)) & 524287u;
            } else {
                // dense: strides {1, G, G*G}; max idx = G^3-1 < hashmap (8-aligned) -> no mod
                idx = c0 + c1 * G + c2 * G * G;
            }
            const float2 e = emb[(size_t)(base + idx)];
            const float w0 = bit0 ? f0 : m0;
            const float w1 = bit1 ? f1 : m1;
            const float w2 = bit2 ? f2 : m2;
            const float w  = __fmul_rn(__fmul_rn(w0, w1), w2);
            a0 = fmaf(w, e.x, a0);
            a1 = fmaf(w, e.y, a1);
        }
        o[2 * l + 0] = a0;
        o[2 * l + 1] = a1;
    }

    // out[b, :] -- 128 B per thread, 8 x float4 stores (base 128B-aligned)
    float4* ov = reinterpret_cast<float4*>(out + (size_t)b * 32u);
#pragma unroll
    for (int j = 0; j < 8; ++j) {
        ov[j] = make_float4(o[4 * j + 0], o[4 * j + 1], o[4 * j + 2], o[4 * j + 3]);
    }
}

extern "C" void kernel_launch(void* const* d_in, const int* in_sizes, int n_in,
                              void* d_out, int out_size, void* d_ws, size_t ws_size,
                              hipStream_t stream) {
    const float*  inp = (const float*)d_in[0];
    const float2* emb = (const float2*)d_in[1];
    float*        out = (float*)d_out;

    // Host-side replication of the reference's level setup (double math, same
    // libm exp2/log2/pow chain as numpy scalars; deterministic -> graph-safe).
    Params p;
    const double PLS = exp2(log2(2048.0 / 16.0) / 15.0);  // per-level scale
    const double S   = log2(PLS);
    unsigned off = 0;
    unsigned hashedMask = 0;
    for (int l = 0; l < NUM_LEVELS; ++l) {
        const double sc_d = exp2((double)l * S) * 16.0 - 1.0;
        const float  sc   = (float)sc_d;
        p.scale[l] = sc;
        const unsigned G = (unsigned)ceilf(sc) + 2u;  // == resolution (verts/dim)
        p.G[l] = G;
        // offsets use res = ceil(16 * PLS^l) + 1 (reference _level_offsets)
        const unsigned res = (unsigned)(ceil(16.0 * pow(PLS, (double)l))) + 1u;
        unsigned long long cube = (unsigned long long)res * res * res;
        unsigned long long nll  = cube < 524288ull ? cube : 524288ull;
        unsigned n = (unsigned)((nll + 7ull) / 8ull * 8ull);
        p.offset[l] = off;
        if ((unsigned long long)G * G * G > (unsigned long long)n) hashedMask |= (1u << l);
        off += n;
    }
    p.hashedMask = hashedMask;

    grid_encode_kernel<<<B_POINTS / BLOCK, BLOCK, 0, stream>>>(inp, emb, out, p);
}

// Round 2
// 721.596 us; speedup vs baseline: 1.5124x; 1.5124x over previous
//
#include <hip/hip_runtime.h>
#include <hip/hip_bf16.h>
#include <math.h>

// GridEncoder (instant-NGP hash grid) forward, level-phased two-pass.
// B = 1<<20 points, 3D input, 16 levels x 2 channels, log2_hashmap=19.
// Pass 1: grid is level-major (4096 blocks/level) so concurrently-resident
//         blocks share one ~4MB hashed-level table -> per-XCD L2 resident.
//         Writes level-major ws[16][B] float2, coalesced.
// Pass 2: transpose ws -> out[B][32] with 128B/thread contiguous writes.

#define NUM_LEVELS 16
#define BLOCK 256
#define B_POINTS (1u << 20)
#define LEVEL_BLOCKS (B_POINTS / BLOCK)  // 4096

struct Params {
    float    scale[NUM_LEVELS];
    unsigned offset[NUM_LEVELS];
    unsigned G[NUM_LEVELS];
    unsigned hashedMask;
};

__device__ __forceinline__ void encode_one(
    const float* __restrict__ inp, const float2* __restrict__ emb,
    unsigned b, float s, unsigned G, unsigned base, bool hashed,
    float& a0, float& a1)
{
    const float i0 = inp[3u * b + 0];
    const float i1 = inp[3u * b + 1];
    const float i2 = inp[3u * b + 2];
    const float x0 = __fmul_rn(__fadd_rn(i0, 1.0f), 0.5f);
    const float x1 = __fmul_rn(__fadd_rn(i1, 1.0f), 0.5f);
    const float x2 = __fmul_rn(__fadd_rn(i2, 1.0f), 0.5f);

    const float p0 = __fadd_rn(__fmul_rn(x0, s), 0.5f);
    const float p1 = __fadd_rn(__fmul_rn(x1, s), 0.5f);
    const float p2 = __fadd_rn(__fmul_rn(x2, s), 0.5f);
    const float g0 = floorf(p0), g1 = floorf(p1), g2 = floorf(p2);
    const float f0 = __fsub_rn(p0, g0);
    const float f1 = __fsub_rn(p1, g1);
    const float f2 = __fsub_rn(p2, g2);
    const unsigned u0 = (unsigned)g0, u1 = (unsigned)g1, u2 = (unsigned)g2;
    const float m0 = __fsub_rn(1.0f, f0);
    const float m1 = __fsub_rn(1.0f, f1);
    const float m2 = __fsub_rn(1.0f, f2);

    a0 = 0.0f; a1 = 0.0f;
#pragma unroll
    for (int k = 0; k < 8; ++k) {
        const unsigned bit0 = (k >> 2) & 1;  // meshgrid 'ij' order
        const unsigned bit1 = (k >> 1) & 1;
        const unsigned bit2 = k & 1;
        const unsigned c0 = u0 + bit0;
        const unsigned c1 = u1 + bit1;
        const unsigned c2 = u2 + bit2;
        unsigned idx;
        if (hashed) {
            idx = (c0 ^ (c1 * 2654435761u) ^ (c2 * 805459861u)) & 524287u;
        } else {
            idx = c0 + c1 * G + c2 * G * G;  // dense: idx < hashmap, no mod
        }
        const float2 e = emb[(size_t)(base + idx)];
        const float w0 = bit0 ? f0 : m0;
        const float w1 = bit1 ? f1 : m1;
        const float w2 = bit2 ? f2 : m2;
        const float w  = __fmul_rn(__fmul_rn(w0, w1), w2);
        a0 = fmaf(w, e.x, a0);
        a1 = fmaf(w, e.y, a1);
    }
}

// ---------------- Pass 1: one (point, level) per thread ----------------
__global__ __launch_bounds__(BLOCK) void grid_level_kernel(
    const float* __restrict__ inp, const float2* __restrict__ emb,
    float2* __restrict__ ws, Params p)
{
    const unsigned blk = blockIdx.x;
    const unsigned l   = blk >> 12;                          // level-major dispatch
    const unsigned b   = ((blk & 4095u) << 8) | threadIdx.x;

    const float    s      = p.scale[l];
    const unsigned G      = p.G[l];
    const unsigned base   = p.offset[l];
    const bool     hashed = (p.hashedMask >> l) & 1u;

    float a0, a1;
    encode_one(inp, emb, b, s, G, base, hashed, a0, a1);
    ws[(size_t)l * B_POINTS + b] = make_float2(a0, a1);      // coalesced 8B
}

// ---------------- Pass 2: transpose ws[16][B] -> out[B][32] ----------------
__global__ __launch_bounds__(BLOCK) void transpose_kernel(
    const float2* __restrict__ ws, float* __restrict__ out)
{
    const unsigned b = blockIdx.x * BLOCK + threadIdx.x;
    float4 r[8];
#pragma unroll
    for (int l = 0; l < NUM_LEVELS; l += 2) {
        const float2 e0 = ws[(size_t)l       * B_POINTS + b];
        const float2 e1 = ws[(size_t)(l + 1) * B_POINTS + b];
        r[l >> 1] = make_float4(e0.x, e0.y, e1.x, e1.y);
    }
    float4* ov = reinterpret_cast<float4*>(out + (size_t)b * 32u);
#pragma unroll
    for (int j = 0; j < 8; ++j) ov[j] = r[j];
}

// ---------------- Fallback: round-1 monolithic kernel ----------------
__global__ __launch_bounds__(BLOCK) void grid_encode_kernel(
    const float* __restrict__ inp, const float2* __restrict__ emb,
    float* __restrict__ out, Params p)
{
    const unsigned b = blockIdx.x * BLOCK + threadIdx.x;
    float o[2 * NUM_LEVELS];
#pragma unroll
    for (int l = 0; l < NUM_LEVELS; ++l) {
        float a0, a1;
        encode_one(inp, emb, b, p.scale[l], p.G[l], p.offset[l],
                   (p.hashedMask >> l) & 1u, a0, a1);
        o[2 * l + 0] = a0;
        o[2 * l + 1] = a1;
    }
    float4* ov = reinterpret_cast<float4*>(out + (size_t)b * 32u);
#pragma unroll
    for (int j = 0; j < 8; ++j)
        ov[j] = make_float4(o[4 * j], o[4 * j + 1], o[4 * j + 2], o[4 * j + 3]);
}

extern "C" void kernel_launch(void* const* d_in, const int* in_sizes, int n_in,
                              void* d_out, int out_size, void* d_ws, size_t ws_size,
                              hipStream_t stream) {
    const float*  inp = (const float*)d_in[0];
    const float2* emb = (const float2*)d_in[1];
    float*        out = (float*)d_out;

    // Host-side replication of reference level setup (same libm chain as numpy).
    Params p;
    const double PLS = exp2(log2(2048.0 / 16.0) / 15.0);
    const double S   = log2(PLS);
    unsigned off = 0, hashedMask = 0;
    for (int l = 0; l < NUM_LEVELS; ++l) {
        const double sc_d = exp2((double)l * S) * 16.0 - 1.0;
        const float  sc   = (float)sc_d;
        p.scale[l] = sc;
        const unsigned G = (unsigned)ceilf(sc) + 2u;
        p.G[l] = G;
        const unsigned res = (unsigned)(ceil(16.0 * pow(PLS, (double)l))) + 1u;
        unsigned long long cube = (unsigned long long)res * res * res;
        unsigned long long nll  = cube < 524288ull ? cube : 524288ull;
        unsigned n = (unsigned)((nll + 7ull) / 8ull * 8ull);
        p.offset[l] = off;
        if ((unsigned long long)G * G * G > (unsigned long long)n) hashedMask |= (1u << l);
        off += n;
    }
    p.hashedMask = hashedMask;

    const size_t ws_needed = (size_t)NUM_LEVELS * B_POINTS * sizeof(float2);  // 128 MB
    if (ws_size >= ws_needed) {
        float2* ws = (float2*)d_ws;
        grid_level_kernel<<<NUM_LEVELS * LEVEL_BLOCKS, BLOCK, 0, stream>>>(inp, emb, ws, p);
        transpose_kernel<<<LEVEL_BLOCKS, BLOCK, 0, stream>>>(ws, out);
    } else {
        grid_encode_kernel<<<LEVEL_BLOCKS, BLOCK, 0, stream>>>(inp, emb, out, p);
    }
}

// Round 3
// 568.475 us; speedup vs baseline: 1.9198x; 1.2694x over previous
//
#include <hip/hip_runtime.h>
#include <hip/hip_bf16.h>
#include <math.h>

// GridEncoder (instant-NGP hash grid) forward, level-phased two-pass.
// Pass 1: level-major dispatch (4096 blocks/level) keeps each ~4MB hashed
//         table L2-resident per XCD. Gather-count reduced by float4 pairing:
//         hash prime for dim0 is 1, so corners (c0,c0+1) with c0 even map to
//         rows {idx, idx^1} = one aligned float4. Dense levels (stride-1 dim0)
//         always pair. Writes level-major ws[16][B] float2, coalesced.
// Pass 2: transpose ws -> out[B][32], one thread per 16B chunk (coalesced
//         1KB/wave stores -- the per-thread-row version was store-divergent).

#define NUM_LEVELS 16
#define BLOCK 256
#define B_POINTS (1u << 20)
#define LEVEL_BLOCKS (B_POINTS / BLOCK)  // 4096
#define P1 2654435761u
#define P2 805459861u
#define HASH_MASK 524287u

struct Params {
    float    scale[NUM_LEVELS];
    unsigned offset[NUM_LEVELS];
    unsigned G[NUM_LEVELS];
    unsigned hashedMask;
};

// ---------------- Pass 1 ----------------
__global__ __launch_bounds__(BLOCK) void grid_level_kernel(
    const float* __restrict__ inp, const float2* __restrict__ emb,
    float2* __restrict__ ws, Params p)
{
    const unsigned blk = blockIdx.x;
    const unsigned l   = blk >> 12;                      // level-major dispatch
    const unsigned b   = ((blk & 4095u) << 8) | threadIdx.x;

    const float    s      = p.scale[l];
    const unsigned G      = p.G[l];
    const unsigned base   = p.offset[l];
    const bool     hashed = (p.hashedMask >> l) & 1u;    // wave-uniform

    const float i0 = inp[3u * b + 0];
    const float i1 = inp[3u * b + 1];
    const float i2 = inp[3u * b + 2];
    const float x0 = __fmul_rn(__fadd_rn(i0, 1.0f), 0.5f);
    const float x1 = __fmul_rn(__fadd_rn(i1, 1.0f), 0.5f);
    const float x2 = __fmul_rn(__fadd_rn(i2, 1.0f), 0.5f);

    const float p0 = __fadd_rn(__fmul_rn(x0, s), 0.5f);
    const float p1 = __fadd_rn(__fmul_rn(x1, s), 0.5f);
    const float p2 = __fadd_rn(__fmul_rn(x2, s), 0.5f);
    const float g0 = floorf(p0), g1 = floorf(p1), g2 = floorf(p2);
    const float f0 = __fsub_rn(p0, g0);
    const float f1 = __fsub_rn(p1, g1);
    const float f2 = __fsub_rn(p2, g2);
    const unsigned u0 = (unsigned)g0, u1 = (unsigned)g1, u2 = (unsigned)g2;
    const float m0 = __fsub_rn(1.0f, f0);
    const float m1 = __fsub_rn(1.0f, f1);
    const float m2 = __fsub_rn(1.0f, f2);

    float a0 = 0.0f, a1 = 0.0f;

    if (hashed) {
        const unsigned h1a = u1 * P1,       h2a = u2 * P2;
        const unsigned h1b = (u1 + 1u) * P1, h2b = (u2 + 1u) * P2;
        if ((u0 & 1u) == 0u) {
            // even u0: corners (u0, u0+1) -> rows {idx, idx^1}: one aligned float4
#pragma unroll
            for (int k = 0; k < 4; ++k) {
                const unsigned b1 = (k >> 1) & 1, b2 = k & 1;
                const unsigned h  = (b1 ? h1b : h1a) ^ (b2 ? h2b : h2a);
                const unsigned idx0 = (u0 ^ h) & HASH_MASK;   // corner c0=u0
                const unsigned base2 = idx0 & ~1u;
                const float4 e4 = *reinterpret_cast<const float4*>(
                    reinterpret_cast<const float*>(emb) + 2u * (base + base2));
                const bool q = (idx0 & 1u);                   // which half is c0=u0
                const float eax = q ? e4.z : e4.x, eay = q ? e4.w : e4.y;
                const float ebx = q ? e4.x : e4.z, eby = q ? e4.y : e4.w;
                const float w12 = __fmul_rn(b1 ? f1 : m1, b2 ? f2 : m2);
                const float wa = __fmul_rn(m0, w12);
                const float wb = __fmul_rn(f0, w12);
                a0 = fmaf(wa, eax, a0); a1 = fmaf(wa, eay, a1);
                a0 = fmaf(wb, ebx, a0); a1 = fmaf(wb, eby, a1);
            }
        } else {
            // odd u0: no pairing possible
#pragma unroll
            for (int k = 0; k < 8; ++k) {
                const unsigned bit0 = (k >> 2) & 1, bit1 = (k >> 1) & 1, bit2 = k & 1;
                const unsigned c0 = u0 + bit0;
                const unsigned h  = (bit1 ? h1b : h1a) ^ (bit2 ? h2b : h2a);
                const unsigned idx = (c0 ^ h) & HASH_MASK;
                const float2 e = emb[(size_t)(base + idx)];
                const float w = __fmul_rn(__fmul_rn(bit0 ? f0 : m0, bit1 ? f1 : m1),
                                          bit2 ? f2 : m2);
                a0 = fmaf(w, e.x, a0); a1 = fmaf(w, e.y, a1);
            }
        }
    } else {
        // dense: dim0 stride 1 -> rows (r, r+1) always adjacent; 8B-aligned float4
        const unsigned GG = G * G;
#pragma unroll
        for (int k = 0; k < 4; ++k) {
            const unsigned b1 = (k >> 1) & 1, b2 = k & 1;
            const unsigned r = u0 + (u1 + b1) * G + (u2 + b2) * GG;  // < G^3-1
            const float4 e4 = *reinterpret_cast<const float4*>(
                reinterpret_cast<const float*>(emb) + 2u * (base + r));
            const float w12 = __fmul_rn(b1 ? f1 : m1, b2 ? f2 : m2);
            const float wa = __fmul_rn(m0, w12);   // corner c0=u0   -> e4.xy
            const float wb = __fmul_rn(f0, w12);   // corner c0=u0+1 -> e4.zw
            a0 = fmaf(wa, e4.x, a0); a1 = fmaf(wa, e4.y, a1);
            a0 = fmaf(wb, e4.z, a0); a1 = fmaf(wb, e4.w, a1);
        }
    }

    ws[(size_t)l * B_POINTS + b] = make_float2(a0, a1);   // coalesced 8B
}

// ---------------- Pass 2: ws[16][B] -> out[B][32], thread per 16B chunk ----
__global__ __launch_bounds__(BLOCK) void transpose_kernel(
    const float2* __restrict__ ws, float* __restrict__ out)
{
    const unsigned t = blockIdx.x * BLOCK + threadIdx.x;  // [0, 8M)
    const unsigned b = t >> 3;
    const unsigned j = t & 7u;                            // level pair index
    const float2 e0 = ws[(size_t)(2u * j)      * B_POINTS + b];
    const float2 e1 = ws[(size_t)(2u * j + 1u) * B_POINTS + b];
    reinterpret_cast<float4*>(out)[t] = make_float4(e0.x, e0.y, e1.x, e1.y);
}

// ---------------- Fallback: monolithic (used only if ws too small) --------
__global__ __launch_bounds__(BLOCK) void grid_encode_kernel(
    const float* __restrict__ inp, const float2* __restrict__ emb,
    float* __restrict__ out, Params p)
{
    const unsigned b = blockIdx.x * BLOCK + threadIdx.x;
    const float i0 = inp[3u * b + 0], i1 = inp[3u * b + 1], i2 = inp[3u * b + 2];
    const float x0 = __fmul_rn(__fadd_rn(i0, 1.0f), 0.5f);
    const float x1 = __fmul_rn(__fadd_rn(i1, 1.0f), 0.5f);
    const float x2 = __fmul_rn(__fadd_rn(i2, 1.0f), 0.5f);
    float o[2 * NUM_LEVELS];
#pragma unroll
    for (int l = 0; l < NUM_LEVELS; ++l) {
        const float s = p.scale[l];
        const unsigned G = p.G[l], base = p.offset[l];
        const bool hashed = (p.hashedMask >> l) & 1u;
        const float p0 = __fadd_rn(__fmul_rn(x0, s), 0.5f);
        const float p1 = __fadd_rn(__fmul_rn(x1, s), 0.5f);
        const float p2 = __fadd_rn(__fmul_rn(x2, s), 0.5f);
        const float g0 = floorf(p0), g1 = floorf(p1), g2 = floorf(p2);
        const float f0 = __fsub_rn(p0, g0), f1 = __fsub_rn(p1, g1), f2 = __fsub_rn(p2, g2);
        const unsigned u0 = (unsigned)g0, u1 = (unsigned)g1, u2 = (unsigned)g2;
        const float m0 = __fsub_rn(1.0f, f0), m1 = __fsub_rn(1.0f, f1), m2 = __fsub_rn(1.0f, f2);
        float a0 = 0.0f, a1 = 0.0f;
#pragma unroll
        for (int k = 0; k < 8; ++k) {
            const unsigned bit0 = (k >> 2) & 1, bit1 = (k >> 1) & 1, bit2 = k & 1;
            const unsigned c0 = u0 + bit0, c1 = u1 + bit1, c2 = u2 + bit2;
            unsigned idx;
            if (hashed) idx = (c0 ^ (c1 * P1) ^ (c2 * P2)) & HASH_MASK;
            else        idx = c0 + c1 * G + c2 * G * G;
            const float2 e = emb[(size_t)(base + idx)];
            const float w = __fmul_rn(__fmul_rn(bit0 ? f0 : m0, bit1 ? f1 : m1),
                                      bit2 ? f2 : m2);
            a0 = fmaf(w, e.x, a0); a1 = fmaf(w, e.y, a1);
        }
        o[2 * l] = a0; o[2 * l + 1] = a1;
    }
    float4* ov = reinterpret_cast<float4*>(out + (size_t)b * 32u);
#pragma unroll
    for (int j = 0; j < 8; ++j)
        ov[j] = make_float4(o[4 * j], o[4 * j + 1], o[4 * j + 2], o[4 * j + 3]);
}

extern "C" void kernel_launch(void* const* d_in, const int* in_sizes, int n_in,
                              void* d_out, int out_size, void* d_ws, size_t ws_size,
                              hipStream_t stream) {
    const float*  inp = (const float*)d_in[0];
    const float2* emb = (const float2*)d_in[1];
    float*        out = (float*)d_out;

    // Host-side replication of reference level setup (same libm chain as numpy).
    Params p;
    const double PLS = exp2(log2(2048.0 / 16.0) / 15.0);
    const double S   = log2(PLS);
    unsigned off = 0, hashedMask = 0;
    for (int l = 0; l < NUM_LEVELS; ++l) {
        const double sc_d = exp2((double)l * S) * 16.0 - 1.0;
        const float  sc   = (float)sc_d;
        p.scale[l] = sc;
        const unsigned G = (unsigned)ceilf(sc) + 2u;
        p.G[l] = G;
        const unsigned res = (unsigned)(ceil(16.0 * pow(PLS, (double)l))) + 1u;
        unsigned long long cube = (unsigned long long)res * res * res;
        unsigned long long nll  = cube < 524288ull ? cube : 524288ull;
        unsigned n = (unsigned)((nll + 7ull) / 8ull * 8ull);
        p.offset[l] = off;
        if ((unsigned long long)G * G * G > (unsigned long long)n) hashedMask |= (1u << l);
        off += n;
    }
    p.hashedMask = hashedMask;

    const size_t ws_needed = (size_t)NUM_LEVELS * B_POINTS * sizeof(float2);  // 128 MB
    if (ws_size >= ws_needed) {
        float2* ws = (float2*)d_ws;
        grid_level_kernel<<<NUM_LEVELS * LEVEL_BLOCKS, BLOCK, 0, stream>>>(inp, emb, ws, p);
        transpose_kernel<<<(B_POINTS * 8) / BLOCK, BLOCK, 0, stream>>>(ws, out);
    } else {
        grid_encode_kernel<<<LEVEL_BLOCKS, BLOCK, 0, stream>>>(inp, emb, out, p);
    }
}

// Round 5
// 558.832 us; speedup vs baseline: 1.9529x; 1.0173x over previous
//
#include <hip/hip_runtime.h>
#include <hip/hip_bf16.h>
#include <math.h>

// GridEncoder (instant-NGP hash grid) forward, level-phased two-pass.
// Pass 1: level-major dispatch (4096 blocks/level) keeps each ~4MB hashed
//         table L2-resident per XCD. float4 pairing halves gathers where the
//         dim0 prime (=1) makes rows adjacent. ws stores nontemporal so the
//         128MB result stream doesn't evict the table from L2.
// Pass 2: LDS-tiled transpose ws[16][B] -> out[B][32]. Per level, reads are
//         contiguous 2KB float4 runs (16 clean streams, not an 8-level
//         straddle per instruction); stores contiguous 4KB/round.

#define NUM_LEVELS 16
#define BLOCK 256
#define B_POINTS (1u << 20)
#define LEVEL_BLOCKS (B_POINTS / BLOCK)  // 4096
#define P1 2654435761u
#define P2 805459861u
#define HASH_MASK 524287u

// pass2 tile
#define T2_PTS 256
#define LROW (T2_PTS + 1)   // float2 per LDS level row; stride 514 words -> bank spread

// native vector type: __builtin_nontemporal_* accepts these (not HIP_vector_type)
typedef float vfloat4 __attribute__((ext_vector_type(4)));

struct Params {
    float    scale[NUM_LEVELS];
    unsigned offset[NUM_LEVELS];
    unsigned G[NUM_LEVELS];
    unsigned hashedMask;
};

// ---------------- Pass 1 ----------------
__global__ __launch_bounds__(BLOCK) void grid_level_kernel(
    const float* __restrict__ inp, const float2* __restrict__ emb,
    float2* __restrict__ ws, Params p)
{
    const unsigned blk = blockIdx.x;
    const unsigned l   = blk >> 12;                      // level-major dispatch
    const unsigned b   = ((blk & 4095u) << 8) | threadIdx.x;

    const float    s      = p.scale[l];
    const unsigned G      = p.G[l];
    const unsigned base   = p.offset[l];
    const bool     hashed = (p.hashedMask >> l) & 1u;    // wave-uniform

    const float i0 = inp[3u * b + 0];
    const float i1 = inp[3u * b + 1];
    const float i2 = inp[3u * b + 2];
    const float x0 = __fmul_rn(__fadd_rn(i0, 1.0f), 0.5f);
    const float x1 = __fmul_rn(__fadd_rn(i1, 1.0f), 0.5f);
    const float x2 = __fmul_rn(__fadd_rn(i2, 1.0f), 0.5f);

    const float p0 = __fadd_rn(__fmul_rn(x0, s), 0.5f);
    const float p1 = __fadd_rn(__fmul_rn(x1, s), 0.5f);
    const float p2 = __fadd_rn(__fmul_rn(x2, s), 0.5f);
    const float g0 = floorf(p0), g1 = floorf(p1), g2 = floorf(p2);
    const float f0 = __fsub_rn(p0, g0);
    const float f1 = __fsub_rn(p1, g1);
    const float f2 = __fsub_rn(p2, g2);
    const unsigned u0 = (unsigned)g0, u1 = (unsigned)g1, u2 = (unsigned)g2;
    const float m0 = __fsub_rn(1.0f, f0);
    const float m1 = __fsub_rn(1.0f, f1);
    const float m2 = __fsub_rn(1.0f, f2);

    float a0 = 0.0f, a1 = 0.0f;

    if (hashed) {
        const unsigned h1a = u1 * P1,        h2a = u2 * P2;
        const unsigned h1b = (u1 + 1u) * P1, h2b = (u2 + 1u) * P2;
        if ((u0 & 1u) == 0u) {
            // even u0: corners (u0, u0+1) -> rows {idx, idx^1}: one aligned float4
#pragma unroll
            for (int k = 0; k < 4; ++k) {
                const unsigned b1 = (k >> 1) & 1, b2 = k & 1;
                const unsigned h  = (b1 ? h1b : h1a) ^ (b2 ? h2b : h2a);
                const unsigned idx0 = (u0 ^ h) & HASH_MASK;
                const unsigned base2 = idx0 & ~1u;
                const vfloat4 e4 = *reinterpret_cast<const vfloat4*>(
                    reinterpret_cast<const float*>(emb) + 2u * (base + base2));
                const bool q = (idx0 & 1u);
                const float eax = q ? e4.z : e4.x, eay = q ? e4.w : e4.y;
                const float ebx = q ? e4.x : e4.z, eby = q ? e4.y : e4.w;
                const float w12 = __fmul_rn(b1 ? f1 : m1, b2 ? f2 : m2);
                const float wa = __fmul_rn(m0, w12);
                const float wb = __fmul_rn(f0, w12);
                a0 = fmaf(wa, eax, a0); a1 = fmaf(wa, eay, a1);
                a0 = fmaf(wb, ebx, a0); a1 = fmaf(wb, eby, a1);
            }
        } else {
#pragma unroll
            for (int k = 0; k < 8; ++k) {
                const unsigned bit0 = (k >> 2) & 1, bit1 = (k >> 1) & 1, bit2 = k & 1;
                const unsigned c0 = u0 + bit0;
                const unsigned h  = (bit1 ? h1b : h1a) ^ (bit2 ? h2b : h2a);
                const unsigned idx = (c0 ^ h) & HASH_MASK;
                const float2 e = emb[(size_t)(base + idx)];
                const float w = __fmul_rn(__fmul_rn(bit0 ? f0 : m0, bit1 ? f1 : m1),
                                          bit2 ? f2 : m2);
                a0 = fmaf(w, e.x, a0); a1 = fmaf(w, e.y, a1);
            }
        }
    } else {
        // dense: dim0 stride 1 -> rows (r, r+1) always adjacent
        const unsigned GG = G * G;
#pragma unroll
        for (int k = 0; k < 4; ++k) {
            const unsigned b1 = (k >> 1) & 1, b2 = k & 1;
            const unsigned r = u0 + (u1 + b1) * G + (u2 + b2) * GG;
            const vfloat4 e4 = *reinterpret_cast<const vfloat4*>(
                reinterpret_cast<const float*>(emb) + 2u * (base + r));
            const float w12 = __fmul_rn(b1 ? f1 : m1, b2 ? f2 : m2);
            const float wa = __fmul_rn(m0, w12);
            const float wb = __fmul_rn(f0, w12);
            a0 = fmaf(wa, e4.x, a0); a1 = fmaf(wa, e4.y, a1);
            a0 = fmaf(wb, e4.z, a0); a1 = fmaf(wb, e4.w, a1);
        }
    }

    // streaming result: nontemporal, don't evict the L2-resident table
    float* wp = reinterpret_cast<float*>(ws + (size_t)l * B_POINTS + b);
    __builtin_nontemporal_store(a0, wp + 0);
    __builtin_nontemporal_store(a1, wp + 1);
}

// ---------------- Pass 2: LDS-tiled transpose ws[16][B] -> out[B][32] ------
__global__ __launch_bounds__(BLOCK) void transpose_kernel(
    const float2* __restrict__ ws, float* __restrict__ out)
{
    __shared__ float2 tile[NUM_LEVELS * LROW];   // 16 x 257 float2 = 32.9 KB
    const unsigned t  = threadIdx.x;
    const unsigned p0 = blockIdx.x * T2_PTS;

    // load: 16 levels x 256 pts = 2048 float4; 8 rounds x 256 threads.
    // per level: 128 consecutive float4 = 2KB contiguous run.
#pragma unroll
    for (int r = 0; r < 8; ++r) {
        const unsigned flat = r * BLOCK + t;
        const unsigned l = flat >> 7;            // 128 float4 per level
        const unsigned i = flat & 127u;          // float4 index within level
        const vfloat4* src = reinterpret_cast<const vfloat4*>(
            ws + (size_t)l * B_POINTS + p0 + 2u * i);
        const vfloat4 v = __builtin_nontemporal_load(src);
        tile[l * LROW + 2u * i]      = make_float2(v.x, v.y);
        tile[l * LROW + 2u * i + 1u] = make_float2(v.z, v.w);
    }
    __syncthreads();

    // store: 256 pts x 8 chunks = 2048 float4; 8 rounds, 4KB contiguous each.
    vfloat4* ov = reinterpret_cast<vfloat4*>(out) + (size_t)p0 * 8u;
#pragma unroll
    for (int r = 0; r < 8; ++r) {
        const unsigned idx = r * BLOCK + t;
        const unsigned pt = idx >> 3;
        const unsigned ch = idx & 7u;            // level pair
        const float2 e0 = tile[(2u * ch)      * LROW + pt];
        const float2 e1 = tile[(2u * ch + 1u) * LROW + pt];
        vfloat4 v; v.x = e0.x; v.y = e0.y; v.z = e1.x; v.w = e1.y;
        __builtin_nontemporal_store(v, ov + idx);
    }
}

// ---------------- Fallback: monolithic (used only if ws too small) --------
__global__ __launch_bounds__(BLOCK) void grid_encode_kernel(
    const float* __restrict__ inp, const float2* __restrict__ emb,
    float* __restrict__ out, Params p)
{
    const unsigned b = blockIdx.x * BLOCK + threadIdx.x;
    const float i0 = inp[3u * b + 0], i1 = inp[3u * b + 1], i2 = inp[3u * b + 2];
    const float x0 = __fmul_rn(__fadd_rn(i0, 1.0f), 0.5f);
    const float x1 = __fmul_rn(__fadd_rn(i1, 1.0f), 0.5f);
    const float x2 = __fmul_rn(__fadd_rn(i2, 1.0f), 0.5f);
    float o[2 * NUM_LEVELS];
#pragma unroll
    for (int l = 0; l < NUM_LEVELS; ++l) {
        const float s = p.scale[l];
        const unsigned G = p.G[l], base = p.offset[l];
        const bool hashed = (p.hashedMask >> l) & 1u;
        const float p0 = __fadd_rn(__fmul_rn(x0, s), 0.5f);
        const float p1 = __fadd_rn(__fmul_rn(x1, s), 0.5f);
        const float p2 = __fadd_rn(__fmul_rn(x2, s), 0.5f);
        const float g0 = floorf(p0), g1 = floorf(p1), g2 = floorf(p2);
        const float f0 = __fsub_rn(p0, g0), f1 = __fsub_rn(p1, g1), f2 = __fsub_rn(p2, g2);
        const unsigned u0 = (unsigned)g0, u1 = (unsigned)g1, u2 = (unsigned)g2;
        const float m0 = __fsub_rn(1.0f, f0), m1 = __fsub_rn(1.0f, f1), m2 = __fsub_rn(1.0f, f2);
        float a0 = 0.0f, a1 = 0.0f;
#pragma unroll
        for (int k = 0; k < 8; ++k) {
            const unsigned bit0 = (k >> 2) & 1, bit1 = (k >> 1) & 1, bit2 = k & 1;
            const unsigned c0 = u0 + bit0, c1 = u1 + bit1, c2 = u2 + bit2;
            unsigned idx;
            if (hashed) idx = (c0 ^ (c1 * P1) ^ (c2 * P2)) & HASH_MASK;
            else        idx = c0 + c1 * G + c2 * G * G;
            const float2 e = emb[(size_t)(base + idx)];
            const float w = __fmul_rn(__fmul_rn(bit0 ? f0 : m0, bit1 ? f1 : m1),
                                      bit2 ? f2 : m2);
            a0 = fmaf(w, e.x, a0); a1 = fmaf(w, e.y, a1);
        }
        o[2 * l] = a0; o[2 * l + 1] = a1;
    }
    float4* ov = reinterpret_cast<float4*>(out + (size_t)b * 32u);
#pragma unroll
    for (int j = 0; j < 8; ++j)
        ov[j] = make_float4(o[4 * j], o[4 * j + 1], o[4 * j + 2], o[4 * j + 3]);
}

extern "C" void kernel_launch(void* const* d_in, const int* in_sizes, int n_in,
                              void* d_out, int out_size, void* d_ws, size_t ws_size,
                              hipStream_t stream) {
    const float*  inp = (const float*)d_in[0];
    const float2* emb = (const float2*)d_in[1];
    float*        out = (float*)d_out;

    // Host-side replication of reference level setup (same libm chain as numpy).
    Params p;
    const double PLS = exp2(log2(2048.0 / 16.0) / 15.0);
    const double S   = log2(PLS);
    unsigned off = 0, hashedMask = 0;
    for (int l = 0; l < NUM_LEVELS; ++l) {
        const double sc_d = exp2((double)l * S) * 16.0 - 1.0;
        const float  sc   = (float)sc_d;
        p.scale[l] = sc;
        const unsigned G = (unsigned)ceilf(sc) + 2u;
        p.G[l] = G;
        const unsigned res = (unsigned)(ceil(16.0 * pow(PLS, (double)l))) + 1u;
        unsigned long long cube = (unsigned long long)res * res * res;
        unsigned long long nll  = cube < 524288ull ? cube : 524288ull;
        unsigned n = (unsigned)((nll + 7ull) / 8ull * 8ull);
        p.offset[l] = off;
        if ((unsigned long long)G * G * G > (unsigned long long)n) hashedMask |= (1u << l);
        off += n;
    }
    p.hashedMask = hashedMask;

    const size_t ws_needed = (size_t)NUM_LEVELS * B_POINTS * sizeof(float2);  // 128 MB
    if (ws_size >= ws_needed) {
        float2* ws = (float2*)d_ws;
        grid_level_kernel<<<NUM_LEVELS * LEVEL_BLOCKS, BLOCK, 0, stream>>>(inp, emb, ws, p);
        transpose_kernel<<<B_POINTS / T2_PTS, BLOCK, 0, stream>>>(ws, out);
    } else {
        grid_encode_kernel<<<LEVEL_BLOCKS, BLOCK, 0, stream>>>(inp, emb, out, p);
    }
}